// Round 5
// baseline (70.939 us; speedup 1.0000x reference)
//
#include <hip/hip_runtime.h>

#define NROW 4096      // 64*64 patch positions
#define NCOL 4225      // 65*65 plane
#define BATCH 8
#define MAGIC 0x13579BDFu

// ws layout: float partial[256]; unsigned flags[256];

// fast tanh for |x| <~ 4: tanh(x) = 1 - 2/(e^{2x}+1), e^{2x} via v_exp_f32,
// v_rcp_f32 instead of precise-division expansion (rel err ~1e-7 << 3e-4 thr)
__device__ __forceinline__ float fast_tanh(float x) {
    float e = __builtin_exp2f(2.885390082f * x);   // 2*log2(e)*x
    return 1.0f - 2.0f * __builtin_amdgcn_rcpf(e + 1.0f);
}

__global__ void __launch_bounds__(256) k_fused(const float* __restrict__ x,
                                               const float* __restrict__ proj_w,
                                               const float* __restrict__ proj_b,
                                               float* __restrict__ out,
                                               float* __restrict__ partial,
                                               unsigned* __restrict__ flags) {
    __shared__ float cs_sh[NCOL];                 // batch-summed plane
    __shared__ __align__(16) float s_sh[NROW];    // tanh scalars (16B for b128)
    __shared__ float c_sh[16];                    // per-row softmax results
    const int tid = threadIdx.x;
    const int bid = blockIdx.x;

    // phase 1: colsum[p] = sum_b x[b,p]; fully unrolled 16x body + 129 tail
#pragma unroll
    for (int k = 0; k < 16; ++k) {
        int p = tid + (k << 8);
        float v = 0.0f;
#pragma unroll
        for (int b = 0; b < BATCH; ++b) v += x[b * NCOL + p];
        cs_sh[p] = v;
    }
    if (tid < NCOL - NROW) {       // 129-element tail
        int p = NROW + tid;
        float v = 0.0f;
#pragma unroll
        for (int b = 0; b < BATCH; ++b) v += x[b * NCOL + p];
        cs_sh[p] = v;
    }
    __syncthreads();

    // phase 2: s[n] = tanh(2x2 patch sum / 32) — 16 per thread, branch-free
#pragma unroll
    for (int k = 0; k < 16; ++k) {
        int n = tid + (k << 8);
        int i = n >> 6, j = n & 63;
        const float* c = &cs_sh[i * 65 + j];
        s_sh[n] = fast_tanh((c[0] + c[1] + c[65] + c[66]) * (1.0f / 32.0f));
    }
    __syncthreads();

    // phase 3: 16 rows/block, 16 lanes/row. ds_read_b128: lane m0 reads 4
    // consecutive scalars; lanes 0-15 span contiguous 256B (2-way bank alias
    // = free), lanes 16/32/48+ broadcast identical addrs. 4x fewer LDS insts
    // than the b32 stride-16 form. 8 accumulators break the fma dep chain.
    const int row = (bid << 4) + (tid >> 4);
    const int m0  = tid & 15;
    const float t = 8.0f * 1.4426950408889634f * s_sh[row];  // fold log2(e)
    const float4* s4 = reinterpret_cast<const float4*>(s_sh);
    float n0 = 0.f, n1 = 0.f, n2 = 0.f, n3 = 0.f;
    float d0 = 0.f, d1 = 0.f, d2 = 0.f, d3 = 0.f;
#pragma unroll 8
    for (int k = 0; k < 64; ++k) {
        float4 v = s4[(k << 4) + m0];
        float e0 = __builtin_exp2f(t * v.x);
        float e1 = __builtin_exp2f(t * v.y);
        float e2 = __builtin_exp2f(t * v.z);
        float e3 = __builtin_exp2f(t * v.w);
        d0 += e0; n0 += e0 * v.x;
        d1 += e1; n1 += e1 * v.y;
        d2 += e2; n2 += e2 * v.z;
        d3 += e3; n3 += e3 * v.w;
    }
    float num = (n0 + n1) + (n2 + n3);
    float den = (d0 + d1) + (d2 + d3);
#pragma unroll
    for (int off = 8; off; off >>= 1) {
        num += __shfl_down(num, off, 16);
        den += __shfl_down(den, off, 16);
    }
    if (m0 == 0) c_sh[tid >> 4] = num / den;
    __syncthreads();

    // phase 4: publish block partial (atomic RMW -> device-coherent; no init)
    if (tid == 0) {
        float bs = 0.0f;
#pragma unroll
        for (int r = 0; r < 16; ++r) bs += c_sh[r];
        atomicExch(&partial[bid], bs);
        __threadfence();
        atomicExch(&flags[bid], MAGIC);
    }

    // phase 5: block 0, wave 0 waits for all partials and finalizes.
    // All other blocks retire unconditionally -> no deadlock under any order.
    if (bid == 0 && tid < 64) {
#pragma unroll
        for (int q = 0; q < 4; ++q) {
            int i = tid + (q << 6);
            while (atomicAdd(&flags[i], 0u) != MAGIC) {}
        }
        __threadfence();
        float acc_c = 0.0f;
#pragma unroll
        for (int q = 0; q < 4; ++q) {
            int i = tid + (q << 6);
            acc_c += atomicAdd(&partial[i], 0.0f);  // coherent read
        }
        float pw = proj_w[tid];  // 64 lanes, one weight each
#pragma unroll
        for (int off = 32; off; off >>= 1) {
            acc_c += __shfl_down(acc_c, off, 64);
            pw    += __shfl_down(pw, off, 64);
        }
        if (tid == 0) {
            float o = (acc_c * (1.0f / (float)NROW)) * pw + proj_b[0];
#pragma unroll
            for (int b = 0; b < BATCH; ++b) out[b] = o;
        }
    }
}

extern "C" void kernel_launch(void* const* d_in, const int* in_sizes, int n_in,
                              void* d_out, int out_size, void* d_ws, size_t ws_size,
                              hipStream_t stream) {
    const float* x      = (const float*)d_in[0];
    const float* proj_w = (const float*)d_in[1];
    const float* proj_b = (const float*)d_in[2];
    float* out = (float*)d_out;

    float*    partial = (float*)d_ws;
    unsigned* flags   = (unsigned*)(partial + 256);

    k_fused<<<256, 256, 0, stream>>>(x, proj_w, proj_b, out, partial, flags);
}